// Round 1
// baseline (5481.391 us; speedup 1.0000x reference)
//
#include <hip/hip_runtime.h>

#define V_   50257
#define VPAD 50304
#define E_   1024
#define H_   16
#define L_   12
#define B_   2
#define T_   1024
#define D_   64
#define NT   2048
#define E3   3072
#define E4   4096

typedef unsigned short u16;
typedef short bf16x8 __attribute__((ext_vector_type(8)));
typedef float f32x4 __attribute__((ext_vector_type(4)));

__device__ __forceinline__ u16 f2bf(float x) {
  unsigned u = __builtin_bit_cast(unsigned, x);
  return (u16)((u + 0x7FFFu + ((u >> 16) & 1u)) >> 16);
}

// ---------------- GEMM: C[M,N] = A[M,K] * B[K,N], B given transposed Bt[N,K] ----------------
// EPI: 0 = bf16 out (+bias), 1 = bf16 gelu(out+bias), 2 = f32 C += out+bias (residual),
//      3 = f32 out (scores), 4 = f32 out+bias with col<Nreal guard (lm head), 5 = bf16 out
template<int BM, int BN, int WM, int WN, int EPI, bool CAUSAL>
__global__ void __launch_bounds__(256)
gemm_bt(const u16* __restrict__ A, const u16* __restrict__ Bt,
        void* __restrict__ Cp, const float* __restrict__ bias,
        int K, int lda, int ldb, int ldc, int Nreal,
        int HH, long aS1, long aS2, long bS1, long bS2, long cS1, long cS2)
{
  constexpr int NW = 4;
  constexpr int ACH = BM / 16;   // number of 1KB staging chunks in A tile
  constexpr int BCH = BN / 16;
  __shared__ __align__(16) u16 As[BM * 32];
  __shared__ __align__(16) u16 Bs[BN * 32];

  const int m0 = blockIdx.y * BM;
  const int n0 = blockIdx.x * BN;
  if (CAUSAL && n0 > m0 + BM - 1) return;   // fully-masked block
  const int z = blockIdx.z;
  const int zb = z / HH, zh = z % HH;
  A  += (long)zb * aS1 + (long)zh * aS2;
  Bt += (long)zb * bS1 + (long)zh * bS2;
  const long coff = (long)zb * cS1 + (long)zh * cS2;

  const int tid  = threadIdx.x;
  const int wave = tid >> 6, lane = tid & 63;
  const int quad = lane >> 4, c16 = lane & 15;
  const int wm = (wave / (BN / WN)) * WM;
  const int wn = (wave % (BN / WN)) * WN;
  const int lrow = lane >> 2;        // 0..15
  const int lcol = (lane & 3) * 8;   // 0,8,16,24

  f32x4 acc[WM/16][WN/16];
  #pragma unroll
  for (int i = 0; i < WM/16; ++i)
    #pragma unroll
    for (int j = 0; j < WN/16; ++j)
      #pragma unroll
      for (int r = 0; r < 4; ++r) acc[i][j][r] = 0.f;

  for (int k0 = 0; k0 < K; k0 += 32) {
    #pragma unroll
    for (int ci = 0; ci < ACH/NW; ++ci) {
      int c = ci * NW + wave;
      const u16* gp = A + (long)(m0 + c*16 + lrow) * lda + k0 + lcol;
      __builtin_amdgcn_global_load_lds((const __attribute__((address_space(1))) void*)gp,
          (__attribute__((address_space(3))) void*)(&As[c*512]), 16, 0, 0);
    }
    #pragma unroll
    for (int ci = 0; ci < BCH/NW; ++ci) {
      int c = ci * NW + wave;
      const u16* gp = Bt + (long)(n0 + c*16 + lrow) * ldb + k0 + lcol;
      __builtin_amdgcn_global_load_lds((const __attribute__((address_space(1))) void*)gp,
          (__attribute__((address_space(3))) void*)(&Bs[c*512]), 16, 0, 0);
    }
    __syncthreads();
    bf16x8 af[WM/16], bfr[WN/16];
    #pragma unroll
    for (int i = 0; i < WM/16; ++i)
      af[i] = *(const bf16x8*)&As[(wm + i*16 + c16) * 32 + quad * 8];
    #pragma unroll
    for (int j = 0; j < WN/16; ++j)
      bfr[j] = *(const bf16x8*)&Bs[(wn + j*16 + c16) * 32 + quad * 8];
    #pragma unroll
    for (int i = 0; i < WM/16; ++i)
      #pragma unroll
      for (int j = 0; j < WN/16; ++j)
        acc[i][j] = __builtin_amdgcn_mfma_f32_16x16x32_bf16(af[i], bfr[j], acc[i][j], 0, 0, 0);
    __syncthreads();
  }

  #pragma unroll
  for (int i = 0; i < WM/16; ++i) {
    #pragma unroll
    for (int j = 0; j < WN/16; ++j) {
      const int row0 = m0 + wm + i*16 + quad*4;
      const int col  = n0 + wn + j*16 + c16;
      float bv = 0.f;
      if (EPI == 0 || EPI == 1 || EPI == 2) bv = bias[col];
      if (EPI == 4) { if (col < Nreal) bv = bias[col]; }
      #pragma unroll
      for (int r = 0; r < 4; ++r) {
        const long off = coff + (long)(row0 + r) * ldc + col;
        const float v = acc[i][j][r];
        if (EPI == 0) ((u16*)Cp)[off] = f2bf(v + bv);
        else if (EPI == 1) {
          float t = v + bv;
          ((u16*)Cp)[off] = f2bf(0.5f * t * (1.f + erff(t * 0.70710678118654752f)));
        }
        else if (EPI == 2) ((float*)Cp)[off] += v + bv;
        else if (EPI == 3) ((float*)Cp)[off] = v;
        else if (EPI == 4) { if (col < Nreal) ((float*)Cp)[off] = v + bv; }
        else ((u16*)Cp)[off] = f2bf(v);
      }
    }
  }
}

// ---------------- weight prep ----------------
__global__ void __launch_bounds__(256)
cast_wte(const float* __restrict__ w, u16* __restrict__ o) {
  long i = ((long)blockIdx.x * 256 + threadIdx.x) * 4;
  if (i >= (long)VPAD * E_) return;
  long v = i >> 10;
  u16 r0, r1, r2, r3;
  if (v < V_) {
    float4 f = *(const float4*)(w + i);
    r0 = f2bf(f.x); r1 = f2bf(f.y); r2 = f2bf(f.z); r3 = f2bf(f.w);
  } else { r0 = r1 = r2 = r3 = 0; }
  *(ushort4*)(o + i) = make_ushort4(r0, r1, r2, r3);
}

// in fp32 [R][C] (batched) -> out bf16 [C][R]
__global__ void __launch_bounds__(256)
transpose_cast(const float* __restrict__ in, u16* __restrict__ out, int R, int C) {
  __shared__ float t[32][33];
  const long bat = (long)blockIdx.z * R * C;
  const int bx = blockIdx.x * 32, by = blockIdx.y * 32;
  const int tx = threadIdx.x & 31, ty = threadIdx.x >> 5;
  #pragma unroll
  for (int i = 0; i < 4; ++i)
    t[ty + i*8][tx] = in[bat + (long)(by + ty + i*8) * C + bx + tx];
  __syncthreads();
  #pragma unroll
  for (int i = 0; i < 4; ++i)
    out[bat + (long)(bx + ty + i*8) * R + by + tx] = f2bf(t[tx][ty + i*8]);
}

// ---------------- embedding ----------------
__global__ void __launch_bounds__(256)
embed_k(const int* __restrict__ idx, const float* __restrict__ wte,
        const float* __restrict__ wpe, float* __restrict__ h) {
  const int tok = blockIdx.x;
  const int t = tok & (T_ - 1);
  const int e = threadIdx.x * 4;
  const long id = idx[tok];
  float4 a = *(const float4*)(wte + id * E_ + e);
  float4 p = *(const float4*)(wpe + (long)t * E_ + e);
  a.x += p.x; a.y += p.y; a.z += p.z; a.w += p.w;
  *(float4*)(h + (long)tok * E_ + e) = a;
}

// ---------------- layernorm (fp32 in, bf16 out) ----------------
__global__ void __launch_bounds__(256)
ln_cast(const float* __restrict__ x, const float* __restrict__ g,
        const float* __restrict__ b, u16* __restrict__ o) {
  const int row = blockIdx.x, tid = threadIdx.x;
  const float* xr = x + (long)row * E_;
  float4 v = *(const float4*)(xr + tid * 4);
  float s  = v.x + v.y + v.z + v.w;
  float ss = v.x*v.x + v.y*v.y + v.z*v.z + v.w*v.w;
  #pragma unroll
  for (int d = 32; d; d >>= 1) { s += __shfl_down(s, d, 64); ss += __shfl_down(ss, d, 64); }
  __shared__ float sb[4], ssb[4], mr[2];
  const int wave = tid >> 6, lane = tid & 63;
  if (!lane) { sb[wave] = s; ssb[wave] = ss; }
  __syncthreads();
  if (!tid) {
    float S = sb[0]+sb[1]+sb[2]+sb[3], SS = ssb[0]+ssb[1]+ssb[2]+ssb[3];
    float mu = S * (1.f / E_);
    float var = SS * (1.f / E_) - mu * mu;
    mr[0] = mu; mr[1] = rsqrtf(var + 1e-5f);
  }
  __syncthreads();
  const float mu = mr[0], rs = mr[1];
  float4 gv = *(const float4*)(g + tid * 4);
  float4 bv = *(const float4*)(b + tid * 4);
  u16 r0 = f2bf((v.x - mu) * rs * gv.x + bv.x);
  u16 r1 = f2bf((v.y - mu) * rs * gv.y + bv.y);
  u16 r2 = f2bf((v.z - mu) * rs * gv.z + bv.z);
  u16 r3 = f2bf((v.w - mu) * rs * gv.w + bv.w);
  *(ushort4*)(o + (long)row * E_ + tid * 4) = make_ushort4(r0, r1, r2, r3);
}

// ---------------- v transpose: qkv[B,T,3E] -> vT[B,H,D,T] ----------------
__global__ void __launch_bounds__(256)
vtrans(const u16* __restrict__ qkv, u16* __restrict__ vT) {
  const int z = blockIdx.y;            // b*H + h
  const int b = z >> 4, h = z & 15;
  const int t0 = blockIdx.x * 64;
  __shared__ u16 tile[64][72];
  const int i  = threadIdx.x >> 2;
  const int jc = (threadIdx.x & 3) * 16;
  const u16* src = qkv + (long)(b * T_ + t0 + i) * E3 + 2 * E_ + h * D_ + jc;
  ((uint4*)&tile[i][jc])[0] = ((const uint4*)src)[0];
  ((uint4*)&tile[i][jc])[1] = ((const uint4*)src)[1];
  __syncthreads();
  const int d = i, ic = jc;
  __align__(16) u16 vals[16];
  #pragma unroll
  for (int u = 0; u < 16; ++u) vals[u] = tile[ic + u][d];
  u16* dst = vT + ((long)z * D_ + d) * T_ + t0 + ic;
  ((uint4*)dst)[0] = ((uint4*)vals)[0];
  ((uint4*)dst)[1] = ((uint4*)vals)[1];
}

// ---------------- causal softmax: fp32 scores -> bf16 probs ----------------
__global__ void __launch_bounds__(256)
softmax_causal(const float* __restrict__ s, u16* __restrict__ p) {
  const long row = blockIdx.x;           // (b*H+h)*T + i
  const int i = (int)(row & (T_ - 1));
  const float* sr = s + row * T_;
  u16* pr = p + row * T_;
  const int tid = threadIdx.x;
  float m = -1e30f, d = 0.f;
  for (int j = tid; j <= i; j += 256) {
    float x = sr[j] * 0.125f;
    if (x > m) { d = d * __expf(m - x) + 1.f; m = x; }
    else d += __expf(x - m);
  }
  #pragma unroll
  for (int o_ = 32; o_; o_ >>= 1) {
    float m2 = __shfl_down(m, o_, 64), d2 = __shfl_down(d, o_, 64);
    float M = fmaxf(m, m2);
    d = d * __expf(m - M) + d2 * __expf(m2 - M);
    m = M;
  }
  __shared__ float sm[4], sd[4], res[2];
  const int wave = tid >> 6, lane = tid & 63;
  if (!lane) { sm[wave] = m; sd[wave] = d; }
  __syncthreads();
  if (!tid) {
    float M = fmaxf(fmaxf(sm[0], sm[1]), fmaxf(sm[2], sm[3]));
    float D = sd[0]*__expf(sm[0]-M) + sd[1]*__expf(sm[1]-M)
            + sd[2]*__expf(sm[2]-M) + sd[3]*__expf(sm[3]-M);
    res[0] = M; res[1] = 1.f / D;
  }
  __syncthreads();
  const float M = res[0], R = res[1];
  for (int j = tid; j < T_; j += 256) {
    float v = (j <= i) ? __expf(sr[j] * 0.125f - M) * R : 0.f;
    pr[j] = f2bf(v);
  }
}

// ---------------- loss ----------------
__global__ void __launch_bounds__(256)
loss_rows(const float* __restrict__ logits, const int* __restrict__ tgt,
          float* __restrict__ nll) {
  const int tok = blockIdx.x, tid = threadIdx.x;
  const float* l = logits + (long)tok * V_;
  float m = -1e30f, d = 0.f;
  for (int j = tid; j < V_; j += 256) {
    float x = l[j];
    if (x > m) { d = d * __expf(m - x) + 1.f; m = x; }
    else d += __expf(x - m);
  }
  #pragma unroll
  for (int o_ = 32; o_; o_ >>= 1) {
    float m2 = __shfl_down(m, o_, 64), d2 = __shfl_down(d, o_, 64);
    float M = fmaxf(m, m2);
    d = d * __expf(m - M) + d2 * __expf(m2 - M);
    m = M;
  }
  __shared__ float sm[4], sd[4];
  const int wave = tid >> 6, lane = tid & 63;
  if (!lane) { sm[wave] = m; sd[wave] = d; }
  __syncthreads();
  if (!tid) {
    float M = fmaxf(fmaxf(sm[0], sm[1]), fmaxf(sm[2], sm[3]));
    float D = sd[0]*__expf(sm[0]-M) + sd[1]*__expf(sm[1]-M)
            + sd[2]*__expf(sm[2]-M) + sd[3]*__expf(sm[3]-M);
    float lt = l[tgt[tok]];
    nll[tok] = -(lt - M - logf(D));
  }
}

__global__ void __launch_bounds__(256)
loss_final(const float* __restrict__ nll, float* __restrict__ out) {
  const int tid = threadIdx.x;
  float s = 0.f;
  for (int j = tid; j < NT; j += 256) s += nll[j];
  #pragma unroll
  for (int o_ = 32; o_; o_ >>= 1) s += __shfl_down(s, o_, 64);
  __shared__ float sb[4];
  const int wave = tid >> 6, lane = tid & 63;
  if (!lane) sb[wave] = s;
  __syncthreads();
  if (!tid) out[0] = (sb[0] + sb[1] + sb[2] + sb[3]) * (1.f / NT);
}

// ---------------- host ----------------
extern "C" void kernel_launch(void* const* d_in, const int* in_sizes, int n_in,
                              void* d_out, int out_size, void* d_ws, size_t ws_size,
                              hipStream_t stream) {
  (void)in_sizes; (void)n_in; (void)out_size; (void)ws_size;
  const int*   idx   = (const int*)d_in[0];
  const int*   tgt   = (const int*)d_in[1];
  const float* wte   = (const float*)d_in[2];
  const float* wpe   = (const float*)d_in[3];
  const float* ln1g  = (const float*)d_in[4];
  const float* ln1b  = (const float*)d_in[5];
  const float* qkvw  = (const float*)d_in[6];
  const float* qkvbi = (const float*)d_in[7];
  const float* ow    = (const float*)d_in[8];
  const float* obi   = (const float*)d_in[9];
  const float* ln2g  = (const float*)d_in[10];
  const float* ln2b  = (const float*)d_in[11];
  const float* upw   = (const float*)d_in[12];
  const float* upbi  = (const float*)d_in[13];
  const float* dww   = (const float*)d_in[14];
  const float* dwbi  = (const float*)d_in[15];
  const float* lnfg  = (const float*)d_in[16];
  const float* lnfb  = (const float*)d_in[17];
  const float* lmb   = (const float*)d_in[18];
  float* out = (float*)d_out;

  char* w = (char*)d_ws;
  size_t off = 0;
  auto alloc = [&](size_t bytes) -> void* {
    void* p = w + off;
    off += (bytes + 255) & ~(size_t)255;
    return p;
  };
  u16*   wteT  = (u16*)alloc((size_t)VPAD * E_ * 2);
  u16*   qkvT  = (u16*)alloc((size_t)L_ * E3 * E_ * 2);
  u16*   oT    = (u16*)alloc((size_t)L_ * E_ * E_ * 2);
  u16*   upT   = (u16*)alloc((size_t)L_ * E4 * E_ * 2);
  u16*   dwT   = (u16*)alloc((size_t)L_ * E_ * E4 * 2);
  float* h     = (float*)alloc((size_t)NT * E_ * 4);
  u16*   xb    = (u16*)alloc((size_t)NT * E_ * 2);
  u16*   qkvx  = (u16*)alloc((size_t)NT * E3 * 2);
  u16*   vT    = (u16*)alloc((size_t)B_ * H_ * D_ * T_ * 2);
  u16*   probs = (u16*)alloc((size_t)B_ * H_ * T_ * T_ * 2);
  u16*   attnb = (u16*)alloc((size_t)NT * E_ * 2);
  u16*   mlpb  = (u16*)alloc((size_t)NT * E4 * 2);
  float* nll   = (float*)alloc((size_t)NT * 4);
  float* scores = out;   // d_out (412 MB) as scratch; logits written afterwards

  // weight prep (ws is re-poisoned every launch, so redo each call)
  cast_wte<<<VPAD * E_ / 1024, 256, 0, stream>>>(wte, wteT);
  transpose_cast<<<dim3(E3/32, E_/32, L_), 256, 0, stream>>>(qkvw, qkvT, E_, E3);
  transpose_cast<<<dim3(E_/32, E_/32, L_), 256, 0, stream>>>(ow,   oT,   E_, E_);
  transpose_cast<<<dim3(E4/32, E_/32, L_), 256, 0, stream>>>(upw,  upT,  E_, E4);
  transpose_cast<<<dim3(E_/32, E4/32, L_), 256, 0, stream>>>(dww,  dwT,  E4, E_);
  embed_k<<<NT, 256, 0, stream>>>(idx, wte, wpe, h);

  for (int l = 0; l < L_; ++l) {
    ln_cast<<<NT, 256, 0, stream>>>(h, ln1g + l*E_, ln1b + l*E_, xb);
    gemm_bt<128,128,64,64,0,false><<<dim3(E3/128, NT/128, 1), 256, 0, stream>>>(
        xb, qkvT + (size_t)l*E3*E_, qkvx, qkvbi + l*E3,
        E_, E_, E_, E3, E3, 1, 0,0, 0,0, 0,0);
    vtrans<<<dim3(T_/64, B_*H_), 256, 0, stream>>>(qkvx, vT);
    gemm_bt<128,128,64,64,3,true><<<dim3(T_/128, T_/128, B_*H_), 256, 0, stream>>>(
        qkvx, qkvx + E_, scores, nullptr,
        D_, E3, E3, T_, T_,
        H_, (long)T_*E3, (long)D_, (long)T_*E3, (long)D_,
        (long)H_*T_*T_, (long)T_*T_);
    softmax_causal<<<B_*H_*T_, 256, 0, stream>>>(scores, probs);
    gemm_bt<128,64,32,64,5,false><<<dim3(1, T_/128, B_*H_), 256, 0, stream>>>(
        probs, vT, attnb, nullptr,
        T_, T_, T_, E_, D_,
        H_, (long)H_*T_*T_, (long)T_*T_, (long)H_*D_*T_, (long)D_*T_,
        (long)T_*E_, (long)D_);
    gemm_bt<128,128,64,64,2,false><<<dim3(E_/128, NT/128, 1), 256, 0, stream>>>(
        attnb, oT + (size_t)l*E_*E_, h, obi + l*E_,
        E_, E_, E_, E_, E_, 1, 0,0, 0,0, 0,0);
    ln_cast<<<NT, 256, 0, stream>>>(h, ln2g + l*E_, ln2b + l*E_, xb);
    gemm_bt<128,128,64,64,1,false><<<dim3(E4/128, NT/128, 1), 256, 0, stream>>>(
        xb, upT + (size_t)l*E4*E_, mlpb, upbi + l*E4,
        E_, E_, E_, E4, E4, 1, 0,0, 0,0, 0,0);
    gemm_bt<128,128,64,64,2,false><<<dim3(E_/128, NT/128, 1), 256, 0, stream>>>(
        mlpb, dwT + (size_t)l*E_*E4, h, dwbi + l*E_,
        E4, E4, E4, E_, E_, 1, 0,0, 0,0, 0,0);
  }

  ln_cast<<<NT, 256, 0, stream>>>(h, lnfg, lnfb, xb);
  gemm_bt<128,128,64,64,4,false><<<dim3(VPAD/128, NT/128, 1), 256, 0, stream>>>(
      xb, wteT, out, lmb,
      E_, E_, E_, V_, V_, 1, 0,0, 0,0, 0,0);
  loss_rows<<<NT, 256, 0, stream>>>(out, tgt, nll);
  loss_final<<<1, 256, 0, stream>>>(nll, out + (size_t)NT * V_);
}